// Round 5
// baseline (150.432 us; speedup 1.0000x reference)
//
#include <hip/hip_runtime.h>
#include <stdint.h>

// MultiHeadAttention fused pipeline for MI355X (gfx950).
// B=2, S=2048, D=1024, H=16, dk=64. fp32 in/out, bf16 MFMA compute.

#define AS1 __attribute__((address_space(1)))
#define AS3 __attribute__((address_space(3)))

typedef unsigned short u16;
typedef short s16x8 __attribute__((ext_vector_type(8)));   // 8 bf16 (4 VGPRs) MFMA frag
typedef float f32x4 __attribute__((ext_vector_type(4)));   // MFMA accumulator
typedef u16   u16x4 __attribute__((ext_vector_type(4)));

#if defined(__has_builtin)
#if __has_builtin(__builtin_amdgcn_exp2f)
#define EXP2F(x) __builtin_amdgcn_exp2f(x)
#else
#define EXP2F(x) exp2f(x)
#endif
#else
#define EXP2F(x) exp2f(x)
#endif

__device__ __forceinline__ u16 f2b(float f) {  // fp32 -> bf16 RNE
  union { float f; uint32_t u; } v;
  v.f = f;
  uint32_t r = (v.u + 0x7fffu + ((v.u >> 16) & 1u)) >> 16;
  return (u16)r;
}

// packed fp32x2 -> bf16x2 (1 VALU op; no builtin on gfx950 -> inline asm, T12)
__device__ __forceinline__ uint32_t cvtpk(float lo, float hi) {
  uint32_t r;
  asm("v_cvt_pk_bf16_f32 %0, %1, %2" : "=v"(r) : "v"(lo), "v"(hi));
  return r;
}

__device__ __forceinline__ f32x4 mfma16(s16x8 a, s16x8 b, f32x4 c) {
  return __builtin_amdgcn_mfma_f32_16x16x32_bf16(a, b, c, 0, 0, 0);
}

__device__ __forceinline__ s16x8 ld_g16(const u16* p) {
  return *reinterpret_cast<const s16x8*>(p);
}

// async global->LDS, 16B per lane. LDS dest must be WAVE-UNIFORM base; HW adds lane*16.
// Global SOURCE is per-lane -> swizzled layouts via pre-swizzled source (m173).
__device__ __forceinline__ void stage16(const u16* g, u16* lds_base) {
  __builtin_amdgcn_global_load_lds((const AS1 unsigned int*)g,
                                   (AS3 unsigned int*)lds_base, 16, 0, 0);
}

// ---------------------------------------------------------------- fused fp32 -> bf16 (all 7 tensors)
struct CvtArgs {
  const float* src[7];
  u16* dst[7];
  int cum[8];   // cumulative block ranges
};

__global__ __launch_bounds__(256) void cvt_all(CvtArgs a) {
  const int bx = blockIdx.x;
  int seg = 0;
#pragma unroll
  for (int i = 1; i < 7; ++i) seg += (bx >= a.cum[i]) ? 1 : 0;
  const int off = (bx - a.cum[seg]) * 256 + threadIdx.x;
  float4 f = reinterpret_cast<const float4*>(a.src[seg])[off];
  union { u16 u[4]; uint64_t q; } o;
  o.u[0] = f2b(f.x); o.u[1] = f2b(f.y); o.u[2] = f2b(f.z); o.u[3] = f2b(f.w);
  reinterpret_cast<uint64_t*>(a.dst[seg])[off] = o.q;
}

// ---------------------------------------------------------------- GEMM  C = A @ W^T + bias
// MODE 0: z in {0,1,2} selects q,k,v. z<2 -> [B,H,S,dk] bf16; z==2 -> VT [B,H,dk,S] bf16.
// MODE 1: out fp32 [4096][1024] (final projection).
template <int MODE>
__global__ __launch_bounds__(256) void gemm_bt(const u16* __restrict__ Abase,
                                               const u16* __restrict__ Wbase,
                                               const float* __restrict__ bias0,
                                               const float* __restrict__ bias1,
                                               const float* __restrict__ bias2,
                                               u16* __restrict__ outb,
                                               u16* __restrict__ vtout,
                                               float* __restrict__ outf) {
  __shared__ u16 As[128 * 32];
  __shared__ u16 Bs[128 * 32];
  const int tid = threadIdx.x;
  const int lane = tid & 63;
  const int w = tid >> 6;
  const int wr = w >> 1, wc = w & 1;       // 2x2 wave grid, each wave 64x64
  const int m0 = blockIdx.y * 128;
  const int n0 = blockIdx.x * 128;
  const int z = (MODE == 0) ? blockIdx.z : 0;

  const u16* A = Abase + (size_t)z * (4096u * 1024u);
  const u16* W = Wbase + (size_t)z * (1024u * 1024u);
  const float* bias = (MODE == 0) ? (z == 0 ? bias0 : (z == 1 ? bias1 : bias2)) : bias0;
  u16* ob = (MODE == 0) ? (outb + (size_t)z * (4096u * 1024u)) : nullptr;

  const int l15 = lane & 15, l4 = lane >> 4;
  const int srow = lane >> 2;
  const int scol = (lane & 3) * 8;
  const int i0 = w * 2, i1 = w * 2 + 1;

  f32x4 acc[4][4];
#pragma unroll
  for (int i = 0; i < 4; ++i)
#pragma unroll
    for (int j = 0; j < 4; ++j) acc[i][j] = {0.f, 0.f, 0.f, 0.f};

  for (int kt = 0; kt < 1024; kt += 32) {
    __syncthreads();
    stage16(A + (size_t)(m0 + i0 * 16 + srow) * 1024 + kt + scol, &As[i0 * 512]);
    stage16(A + (size_t)(m0 + i1 * 16 + srow) * 1024 + kt + scol, &As[i1 * 512]);
    stage16(W + (size_t)(n0 + i0 * 16 + srow) * 1024 + kt + scol, &Bs[i0 * 512]);
    stage16(W + (size_t)(n0 + i1 * 16 + srow) * 1024 + kt + scol, &Bs[i1 * 512]);
    __syncthreads();

    s16x8 af[4], bf[4];
#pragma unroll
    for (int mi = 0; mi < 4; ++mi)
      af[mi] = *(const s16x8*)&As[(wr * 64 + mi * 16 + l15) * 32 + l4 * 8];
#pragma unroll
    for (int ni = 0; ni < 4; ++ni)
      bf[ni] = *(const s16x8*)&Bs[(wc * 64 + ni * 16 + l15) * 32 + l4 * 8];
    __builtin_amdgcn_s_setprio(1);
#pragma unroll
    for (int mi = 0; mi < 4; ++mi)
#pragma unroll
      for (int ni = 0; ni < 4; ++ni)
        acc[mi][ni] = mfma16(af[mi], bf[ni], acc[mi][ni]);
    __builtin_amdgcn_s_setprio(0);
  }

#pragma unroll
  for (int ni = 0; ni < 4; ++ni) {
    const int col = n0 + wc * 64 + ni * 16 + l15;
    const float bv = bias[col];
#pragma unroll
    for (int mi = 0; mi < 4; ++mi) {
      const int row0 = m0 + wr * 64 + mi * 16 + l4 * 4;
      if (MODE == 0 && z == 2) {
        // V projection -> VT [B,H,dk,S]: rows r are contiguous in s -> packed store
        const int b = row0 >> 11, s0 = row0 & 2047;
        const int h = col >> 6, d = col & 63;
        u16x4 pk = {f2b(acc[mi][ni][0] + bv), f2b(acc[mi][ni][1] + bv),
                    f2b(acc[mi][ni][2] + bv), f2b(acc[mi][ni][3] + bv)};
        *(u16x4*)&vtout[((size_t)(b * 16 + h) * 64 + d) * 2048 + s0] = pk;
      } else {
#pragma unroll
        for (int r = 0; r < 4; ++r) {
          const float val = acc[mi][ni][r] + bv;
          const int row = row0 + r;
          if (MODE == 0) {
            const int b = row >> 11, s = row & 2047;
            const int h = col >> 6, d = col & 63;
            ob[((size_t)(b * 16 + h) * 2048 + s) * 64 + d] = f2b(val);
          } else {
            outf[(size_t)row * 1024 + col] = val;
          }
        }
      }
    }
  }
}

// ---------------------------------------------------------------- flash attention
// 8 waves x 16 q-rows = 128 q/block; grid (16,32) = 512 blocks = 2 blocks/CU
// = 16 waves/CU. KVBLK=64, K/V double-buffered in LDS (XOR-chunk-swizzled via
// pre-swizzled global source). Swapped QK^T (lane l15 owns q-row). P stays
// IN REGISTER: we define the PV k-order as "each lane's own score values"
// (key = nk*16 + 4*l4 + r) -- MFMA only needs A/B to agree on the
// (lane,elem)->k map, and V's LDS read is addressed to match. 4 cvt_pk per
// 32-key chunk, no P LDS, no cross-lane exchange.
// q,k: [B,H,S,dk] bf16. vT: [B,H,dk,S] bf16. out ao: bf16 [B*S][1024].
__global__ __launch_bounds__(512, 4) void fattn(const u16* __restrict__ qp,
                                                const u16* __restrict__ kp,
                                                const u16* __restrict__ vt,
                                                u16* __restrict__ ao) {
  __shared__ u16 Kt[2][4096];               // 64 keys x 64 dk, chunk-swizzled
  __shared__ u16 Vt[2][4096];               // 64 d    x 64 keys, chunk-swizzled

  const int lane = threadIdx.x & 63;
  const int w = threadIdx.x >> 6;           // 0..7
  const int bh = blockIdx.y;
  const int b = bh >> 4, h = bh & 15;
  const int q0 = blockIdx.x * 128 + w * 16;
  const u16* qb = qp + (size_t)bh * (2048 * 64);
  const u16* kb = kp + (size_t)bh * (2048 * 64);
  const u16* vb = vt + (size_t)bh * (64 * 2048);
  const int l15 = lane & 15, l4 = lane >> 4;
  const float KSC = 0.18033688011112042f;   // log2(e) / sqrt(dk)
  const float THR = 8.0f;                   // defer-max threshold (T13)

  // staging: wave w stages storage chunks [w*64, w*64+64) of each 8KB tile.
  // chunk s -> row s>>3, storage col s&7, logical col = (s&7) ^ (row&7).
  const int srow = (w << 3) + (lane >> 3);
  const int c0 = (((lane & 7) ^ (srow & 7)) << 3);   // logical col in elements

  // Q fragments (persistent): B-operand, lane l15 = q row, l4*8 = k offset
  s16x8 qa[2];
#pragma unroll
  for (int ks = 0; ks < 2; ++ks)
    qa[ks] = ld_g16(qb + (size_t)(q0 + l15) * 64 + ks * 32 + l4 * 8);

  f32x4 o[4];                               // O[q=l4*4+r][d=ni*16+l15]
  float mrun = -1e30f, lrun = 0.f;          // per-lane state for q = l15
#pragma unroll
  for (int ni = 0; ni < 4; ++ni) o[ni] = {0.f, 0.f, 0.f, 0.f};

  // prologue: stage tile 0
  stage16(kb + (size_t)srow * 64 + c0, &Kt[0][w * 512]);
  stage16(vb + (size_t)srow * 2048 + c0, &Vt[0][w * 512]);
  __syncthreads();

  for (int t = 0; t < 32; ++t) {
    const int cur = t & 1;
    if (t + 1 < 32) {                       // issue next tile early; hides under compute
      const int kk = (t + 1) << 6;
      stage16(kb + (size_t)(kk + srow) * 64 + c0, &Kt[cur ^ 1][w * 512]);
      stage16(vb + (size_t)srow * 2048 + kk + c0, &Vt[cur ^ 1][w * 512]);
    }

    // ---- QK^T (swapped): sc[nk] = D[key][q], key = nk*16+l4*4+r, q = l15
    f32x4 sc[4];
#pragma unroll
    for (int nk = 0; nk < 4; ++nk) sc[nk] = {0.f, 0.f, 0.f, 0.f};
#pragma unroll
    for (int ks = 0; ks < 2; ++ks) {
      s16x8 kf[4];
#pragma unroll
      for (int nk = 0; nk < 4; ++nk) {
        const int row = nk * 16 + l15;
        const int sc_ = (((ks << 2) | l4) ^ (l15 & 7)) << 3;
        kf[nk] = *(const s16x8*)&Kt[cur][row * 64 + sc_];
      }
      __builtin_amdgcn_s_setprio(1);
#pragma unroll
      for (int nk = 0; nk < 4; ++nk)
        sc[nk] = mfma16(kf[nk], qa[ks], sc[nk]);
      __builtin_amdgcn_s_setprio(0);
    }

    // ---- per-q max: in-lane over 16 keys, then xor 16/32 across l4 groups
    float m01 = fmaxf(fmaxf(sc[0][0], sc[0][1]), fmaxf(sc[0][2], sc[0][3]));
    float m23 = fmaxf(fmaxf(sc[1][0], sc[1][1]), fmaxf(sc[1][2], sc[1][3]));
    float m45 = fmaxf(fmaxf(sc[2][0], sc[2][1]), fmaxf(sc[2][2], sc[2][3]));
    float m67 = fmaxf(fmaxf(sc[3][0], sc[3][1]), fmaxf(sc[3][2], sc[3][3]));
    float m = fmaxf(fmaxf(m01, m23), fmaxf(m45, m67));
    m = fmaxf(m, __shfl_xor(m, 16));
    m = fmaxf(m, __shfl_xor(m, 32));
    const float smax = m * KSC;

    // ---- defer-max rescale (T13)
    if (__any(smax > mrun + THR)) {
      float mn = fmaxf(mrun, smax);
      float alpha = EXP2F(mrun - mn);
      mrun = mn;
      lrun *= alpha;
#pragma unroll
      for (int r = 0; r < 4; ++r) {
        float ar = __shfl(alpha, l4 * 4 + r);
#pragma unroll
        for (int ni = 0; ni < 4; ++ni) o[ni][r] *= ar;
      }
    }

    // ---- P = exp2(sc*KSC - m): lane-local, packed in-register (no LDS)
    float p[4][4];
    float ps = 0.f;
#pragma unroll
    for (int nk = 0; nk < 4; ++nk) {
#pragma unroll
      for (int r = 0; r < 4; ++r) {
        p[nk][r] = EXP2F(fmaf(sc[nk][r], KSC, -mrun));
      }
      ps += (p[nk][0] + p[nk][1]) + (p[nk][2] + p[nk][3]);
    }
    {
      float s = ps;
      s += __shfl_xor(s, 16);
      s += __shfl_xor(s, 32);
      lrun += s;
    }

    // ---- PV: o += P @ vT with self-owned-key order.
    // k-map per 32-chunk ks: elem j<4 -> key ks*32 + 4*l4 + j;
    //                        elem j>=4 -> key ks*32 + 16 + 4*l4 + (j-4).
#pragma unroll
    for (int ks = 0; ks < 2; ++ks) {
      union { uint32_t d[4]; s16x8 v; } pa;
      pa.d[0] = cvtpk(p[2 * ks][0], p[2 * ks][1]);
      pa.d[1] = cvtpk(p[2 * ks][2], p[2 * ks][3]);
      pa.d[2] = cvtpk(p[2 * ks + 1][0], p[2 * ks + 1][1]);
      pa.d[3] = cvtpk(p[2 * ks + 1][2], p[2 * ks + 1][3]);
      s16x8 vf[4];
#pragma unroll
      for (int ni = 0; ni < 4; ++ni) {
        const int row = ni * 16 + l15;
        const int rs = row & 7;
        const int clo = ((4 * ks + (l4 >> 1)) ^ rs) << 3;        // elem offset of chunk
        const int chi = ((4 * ks + 2 + (l4 >> 1)) ^ rs) << 3;
        const int sub = (l4 & 1) << 2;                           // 4-elem sub-offset
        union { struct { u16x4 lo, hi; } s; s16x8 v; } vv;
        vv.s.lo = *(const u16x4*)&Vt[cur][row * 64 + clo + sub];
        vv.s.hi = *(const u16x4*)&Vt[cur][row * 64 + chi + sub];
        vf[ni] = vv.v;
      }
      __builtin_amdgcn_s_setprio(1);
#pragma unroll
      for (int ni = 0; ni < 4; ++ni)
        o[ni] = mfma16(pa.v, vf[ni], o[ni]);
      __builtin_amdgcn_s_setprio(0);
    }

    __syncthreads();   // all reads of buf `cur` done; next-tile stage (vmcnt) drained
  }

  // ---- epilogue: normalize and store bf16 [B*S][1024]
#pragma unroll
  for (int r = 0; r < 4; ++r) {
    float lr = __shfl(lrun, l4 * 4 + r);
    float inv = 1.0f / lr;
    int row = b * 2048 + q0 + l4 * 4 + r;
#pragma unroll
    for (int ni = 0; ni < 4; ++ni)
      ao[(size_t)row * 1024 + h * 64 + ni * 16 + l15] = f2b(o[ni][r] * inv);
  }
}

// ---------------------------------------------------------------- host
extern "C" void kernel_launch(void* const* d_in, const int* in_sizes, int n_in,
                              void* d_out, int out_size, void* d_ws, size_t ws_size,
                              hipStream_t stream) {
  const float* Q  = (const float*)d_in[0];
  const float* K  = (const float*)d_in[1];
  const float* V  = (const float*)d_in[2];
  const float* Wq = (const float*)d_in[3];
  const float* bq = (const float*)d_in[4];
  const float* Wk = (const float*)d_in[5];
  const float* bk = (const float*)d_in[6];
  const float* Wv = (const float*)d_in[7];
  const float* bv = (const float*)d_in[8];
  const float* Wo = (const float*)d_in[9];
  const float* bo = (const float*)d_in[10];
  float* out = (float*)d_out;

  const size_t NI = (size_t)4096 * 1024;
  const size_t NW = (size_t)1024 * 1024;
  u16* XB  = (u16*)d_ws;          // Qb,Kb,Vb bf16 (3*NI)
  u16* WB  = XB + 3 * NI;         // Wq,Wk,Wv,Wo bf16 (4*NW)
  u16* QKV = WB + 4 * NW;         // q,k [B,H,S,dk] bf16 (slot 2 unused)
  u16* VT  = QKV + 3 * NI;        // vT [B,H,dk,S] bf16
  u16* AO  = VT + NI;             // attention output bf16 [B*S][D]

  CvtArgs ca;
  ca.src[0] = Q;  ca.dst[0] = XB;
  ca.src[1] = K;  ca.dst[1] = XB + NI;
  ca.src[2] = V;  ca.dst[2] = XB + 2 * NI;
  ca.src[3] = Wq; ca.dst[3] = WB;
  ca.src[4] = Wk; ca.dst[4] = WB + NW;
  ca.src[5] = Wv; ca.dst[5] = WB + 2 * NW;
  ca.src[6] = Wo; ca.dst[6] = WB + 3 * NW;
  ca.cum[0] = 0;     ca.cum[1] = 4096;  ca.cum[2] = 8192;  ca.cum[3] = 12288;
  ca.cum[4] = 13312; ca.cum[5] = 14336; ca.cum[6] = 15360; ca.cum[7] = 16384;
  cvt_all<<<dim3(16384), 256, 0, stream>>>(ca);

  // q,k,v projections (z = 0,1,2); z==2 writes VT directly
  gemm_bt<0><<<dim3(8, 32, 3), 256, 0, stream>>>(XB, WB, bq, bk, bv, QKV, VT, nullptr);
  // attention
  fattn<<<dim3(16, 32), 512, 0, stream>>>(QKV, QKV + NI, VT, AO);
  // output projection
  gemm_bt<1><<<dim3(8, 32, 1), 256, 0, stream>>>(AO, WB + 3 * NW, bo, nullptr, nullptr,
                                                 nullptr, nullptr, out);
}

// Round 6
// 145.481 us; speedup vs baseline: 1.0340x; 1.0340x over previous
//
#include <hip/hip_runtime.h>
#include <stdint.h>

// MultiHeadAttention fused pipeline for MI355X (gfx950).
// B=2, S=2048, D=1024, H=16, dk=64. fp32 in/out, bf16 MFMA compute.

#define AS1 __attribute__((address_space(1)))
#define AS3 __attribute__((address_space(3)))

typedef unsigned short u16;
typedef short s16x8 __attribute__((ext_vector_type(8)));   // 8 bf16 (4 VGPRs) MFMA frag
typedef float f32x4 __attribute__((ext_vector_type(4)));   // MFMA accumulator
typedef u16   u16x4 __attribute__((ext_vector_type(4)));

#if defined(__has_builtin)
#if __has_builtin(__builtin_amdgcn_exp2f)
#define EXP2F(x) __builtin_amdgcn_exp2f(x)
#else
#define EXP2F(x) exp2f(x)
#endif
#else
#define EXP2F(x) exp2f(x)
#endif

__device__ __forceinline__ u16 f2b(float f) {  // fp32 -> bf16 RNE
  union { float f; uint32_t u; } v;
  v.f = f;
  uint32_t r = (v.u + 0x7fffu + ((v.u >> 16) & 1u)) >> 16;
  return (u16)r;
}

// packed fp32x2 -> bf16x2 (1 VALU op; no builtin on gfx950 -> inline asm, T12)
__device__ __forceinline__ uint32_t cvtpk(float lo, float hi) {
  uint32_t r;
  asm("v_cvt_pk_bf16_f32 %0, %1, %2" : "=v"(r) : "v"(lo), "v"(hi));
  return r;
}

__device__ __forceinline__ f32x4 mfma16(s16x8 a, s16x8 b, f32x4 c) {
  return __builtin_amdgcn_mfma_f32_16x16x32_bf16(a, b, c, 0, 0, 0);
}

__device__ __forceinline__ s16x8 ld_g16(const u16* p) {
  return *reinterpret_cast<const s16x8*>(p);
}

// async global->LDS, 16B per lane. LDS dest must be WAVE-UNIFORM base; HW adds lane*16.
// Global SOURCE is per-lane -> swizzled layouts via pre-swizzled source (m173).
__device__ __forceinline__ void stage16(const u16* g, u16* lds_base) {
  __builtin_amdgcn_global_load_lds((const AS1 unsigned int*)g,
                                   (AS3 unsigned int*)lds_base, 16, 0, 0);
}

// ---------------------------------------------------------------- fused fp32 -> bf16 (all 7 tensors)
struct CvtArgs {
  const float* src[7];
  u16* dst[7];
  int cum[8];   // cumulative block ranges
};

__global__ __launch_bounds__(256) void cvt_all(CvtArgs a) {
  const int bx = blockIdx.x;
  int seg = 0;
#pragma unroll
  for (int i = 1; i < 7; ++i) seg += (bx >= a.cum[i]) ? 1 : 0;
  const int off = (bx - a.cum[seg]) * 256 + threadIdx.x;
  float4 f = reinterpret_cast<const float4*>(a.src[seg])[off];
  union { u16 u[4]; uint64_t q; } o;
  o.u[0] = f2b(f.x); o.u[1] = f2b(f.y); o.u[2] = f2b(f.z); o.u[3] = f2b(f.w);
  reinterpret_cast<uint64_t*>(a.dst[seg])[off] = o.q;
}

// ---------------------------------------------------------------- GEMM  C = A @ W^T + bias
// MODE 0: z in {0,1,2} selects q,k,v.
//   z==0 -> q [B,H,S,dk] bf16, values pre-scaled by KSC = log2(e)/sqrt(dk)
//   z==1 -> k [B,H,S,dk] bf16
//   z==2 -> VT [B,H,dk,S] bf16 with keys PERMUTED: key (32ks+16hi+4g+r) stored at
//           pos (32ks+8g+4hi+r)  -> fattn PV B-frag is one contiguous b128.
// MODE 1: out fp32 [4096][1024] (final projection).
// K-loop is double-buffered (stage next tile before compute, 1 barrier/iter).
template <int MODE>
__global__ __launch_bounds__(256) void gemm_bt(const u16* __restrict__ Abase,
                                               const u16* __restrict__ Wbase,
                                               const float* __restrict__ bias0,
                                               const float* __restrict__ bias1,
                                               const float* __restrict__ bias2,
                                               u16* __restrict__ outb,
                                               u16* __restrict__ vtout,
                                               float* __restrict__ outf) {
  __shared__ u16 As[2][4096];
  __shared__ u16 Bs[2][4096];
  const int tid = threadIdx.x;
  const int lane = tid & 63;
  const int w = tid >> 6;
  const int wr = w >> 1, wc = w & 1;       // 2x2 wave grid, each wave 64x64
  const int m0 = blockIdx.y * 128;
  const int n0 = blockIdx.x * 128;
  const int z = (MODE == 0) ? blockIdx.z : 0;
  const float QSC = 0.18033688011112042f;  // log2(e) / sqrt(dk)

  const u16* A = Abase + (size_t)z * (4096u * 1024u);
  const u16* W = Wbase + (size_t)z * (1024u * 1024u);
  const float* bias = (MODE == 0) ? (z == 0 ? bias0 : (z == 1 ? bias1 : bias2)) : bias0;
  u16* ob = (MODE == 0) ? (outb + (size_t)z * (4096u * 1024u)) : nullptr;

  const int l15 = lane & 15, l4 = lane >> 4;
  const int srow = lane >> 2;
  const int scol = (lane & 3) * 8;
  const int i0 = w * 2, i1 = w * 2 + 1;

  const u16* gA0 = A + (size_t)(m0 + i0 * 16 + srow) * 1024 + scol;
  const u16* gA1 = A + (size_t)(m0 + i1 * 16 + srow) * 1024 + scol;
  const u16* gB0 = W + (size_t)(n0 + i0 * 16 + srow) * 1024 + scol;
  const u16* gB1 = W + (size_t)(n0 + i1 * 16 + srow) * 1024 + scol;

  f32x4 acc[4][4];
#pragma unroll
  for (int i = 0; i < 4; ++i)
#pragma unroll
    for (int j = 0; j < 4; ++j) acc[i][j] = {0.f, 0.f, 0.f, 0.f};

  // prologue: stage K-tile 0
  stage16(gA0, &As[0][i0 * 512]);
  stage16(gA1, &As[0][i1 * 512]);
  stage16(gB0, &Bs[0][i0 * 512]);
  stage16(gB1, &Bs[0][i1 * 512]);
  __syncthreads();

#pragma unroll 2
  for (int t = 0; t < 32; ++t) {
    const int cur = t & 1;
    if (t + 1 < 32) {                       // issue next tile; hides under MFMA
      const int kt = (t + 1) * 32;
      stage16(gA0 + kt, &As[cur ^ 1][i0 * 512]);
      stage16(gA1 + kt, &As[cur ^ 1][i1 * 512]);
      stage16(gB0 + kt, &Bs[cur ^ 1][i0 * 512]);
      stage16(gB1 + kt, &Bs[cur ^ 1][i1 * 512]);
    }
    s16x8 af[4], bf[4];
#pragma unroll
    for (int mi = 0; mi < 4; ++mi)
      af[mi] = *(const s16x8*)&As[cur][(wr * 64 + mi * 16 + l15) * 32 + l4 * 8];
#pragma unroll
    for (int ni = 0; ni < 4; ++ni)
      bf[ni] = *(const s16x8*)&Bs[cur][(wc * 64 + ni * 16 + l15) * 32 + l4 * 8];
    __builtin_amdgcn_s_setprio(1);
#pragma unroll
    for (int mi = 0; mi < 4; ++mi)
#pragma unroll
      for (int ni = 0; ni < 4; ++ni)
        acc[mi][ni] = mfma16(af[mi], bf[ni], acc[mi][ni]);
    __builtin_amdgcn_s_setprio(0);
    __syncthreads();
  }

#pragma unroll
  for (int ni = 0; ni < 4; ++ni) {
    const int col = n0 + wc * 64 + ni * 16 + l15;
    const float bv = bias[col];
#pragma unroll
    for (int mi = 0; mi < 4; ++mi) {
      const int row0 = m0 + wr * 64 + mi * 16 + l4 * 4;
      if (MODE == 0 && z == 2) {
        // V -> VT [B,H,dk,S], permuted key order (see header comment)
        const int b = row0 >> 11, s0 = row0 & 2047;
        const int pos0 = (s0 & ~31) | ((s0 & 12) << 1) | ((s0 & 16) >> 2);
        const int h = col >> 6, d = col & 63;
        u16x4 pk = {f2b(acc[mi][ni][0] + bv), f2b(acc[mi][ni][1] + bv),
                    f2b(acc[mi][ni][2] + bv), f2b(acc[mi][ni][3] + bv)};
        *(u16x4*)&vtout[((size_t)(b * 16 + h) * 64 + d) * 2048 + pos0] = pk;
      } else {
#pragma unroll
        for (int r = 0; r < 4; ++r) {
          float val = acc[mi][ni][r] + bv;
          const int row = row0 + r;
          if (MODE == 0) {
            if (z == 0) val *= QSC;          // fold softmax scale into q
            const int b = row >> 11, s = row & 2047;
            const int h = col >> 6, d = col & 63;
            ob[((size_t)(b * 16 + h) * 2048 + s) * 64 + d] = f2b(val);
          } else {
            outf[(size_t)row * 1024 + col] = val;
          }
        }
      }
    }
  }
}

// ---------------------------------------------------------------- flash attention
// 8 waves x 16 q-rows = 128 q/block; grid (16,32) = 512 blocks = 2 blocks/CU.
// KVBLK=64, K/V double-buffered LDS (XOR-chunk-swizzled via pre-swizzled source).
// Swapped QK^T (lane l15 owns q-row, scores pre-scaled via q). P in REGISTER
// with self-owned-key order; V pre-permuted in global so the matching B-frag is
// one b128 read. Softmax denominator accumulated by MFMA against ones (same
// layout as o -> no shuffles). Loop unrolled x2 so `cur` is compile-time and
// all LDS addresses hoist.
__global__ __launch_bounds__(512, 4) void fattn(const u16* __restrict__ qp,
                                                const u16* __restrict__ kp,
                                                const u16* __restrict__ vt,
                                                u16* __restrict__ ao) {
  __shared__ u16 Kt[2][4096];               // 64 keys x 64 dk, chunk-swizzled
  __shared__ u16 Vt[2][4096];               // 64 d    x 64 keys (perm), chunk-swizzled

  const int lane = threadIdx.x & 63;
  const int w = threadIdx.x >> 6;           // 0..7
  const int bh = blockIdx.y;
  const int b = bh >> 4, h = bh & 15;
  const int q0 = blockIdx.x * 128 + w * 16;
  const u16* qb = qp + (size_t)bh * (2048 * 64);
  const u16* kb = kp + (size_t)bh * (2048 * 64);
  const u16* vb = vt + (size_t)bh * (64 * 2048);
  const int l15 = lane & 15, l4 = lane >> 4;
  const float THR = 8.0f;                   // defer-max threshold (T13), log2 units

  // staging: wave w stages storage chunks [w*64, w*64+64) of each 8KB tile.
  // chunk s -> row s>>3, storage col s&7, logical col = (s&7) ^ (row&7).
  const int srow = (w << 3) + (lane >> 3);
  const int c0 = (((lane & 7) ^ (srow & 7)) << 3);   // logical col in elements

  // Q fragments (persistent): B-operand, lane l15 = q row, l4*8 = k offset.
  // q values already scaled by log2(e)/sqrt(dk).
  s16x8 qa[2];
#pragma unroll
  for (int ks = 0; ks < 2; ++ks)
    qa[ks] = ld_g16(qb + (size_t)(q0 + l15) * 64 + ks * 32 + l4 * 8);

  s16x8 onesf = {(short)0x3F80, (short)0x3F80, (short)0x3F80, (short)0x3F80,
                 (short)0x3F80, (short)0x3F80, (short)0x3F80, (short)0x3F80};

  f32x4 o[4];                               // O[q=l4*4+r][d=ni*16+l15]
  f32x4 o5 = {0.f, 0.f, 0.f, 0.f};          // softmax denominator (same layout)
  float mrun = -1e30f;                      // per-lane running max for q = l15
#pragma unroll
  for (int ni = 0; ni < 4; ++ni) o[ni] = {0.f, 0.f, 0.f, 0.f};

  // prologue: stage tile 0
  stage16(kb + (size_t)srow * 64 + c0, &Kt[0][w * 512]);
  stage16(vb + (size_t)srow * 2048 + c0, &Vt[0][w * 512]);
  __syncthreads();

#pragma unroll 2
  for (int t = 0; t < 32; ++t) {
    const int cur = t & 1;
    if (t + 1 < 32) {                       // issue next tile early
      const int kk = (t + 1) << 6;
      stage16(kb + (size_t)(kk + srow) * 64 + c0, &Kt[cur ^ 1][w * 512]);
      stage16(vb + (size_t)srow * 2048 + kk + c0, &Vt[cur ^ 1][w * 512]);
    }

    // ---- QK^T (swapped): sc[nk] = D[key][q], key = nk*16+l4*4+r, q = l15
    f32x4 sc[4];
#pragma unroll
    for (int nk = 0; nk < 4; ++nk) sc[nk] = {0.f, 0.f, 0.f, 0.f};
#pragma unroll
    for (int ks = 0; ks < 2; ++ks) {
      s16x8 kf[4];
#pragma unroll
      for (int nk = 0; nk < 4; ++nk) {
        const int row = nk * 16 + l15;
        const int scx = (((ks << 2) | l4) ^ (l15 & 7)) << 3;
        kf[nk] = *(const s16x8*)&Kt[cur][row * 64 + scx];
      }
      __builtin_amdgcn_s_setprio(1);
#pragma unroll
      for (int nk = 0; nk < 4; ++nk)
        sc[nk] = mfma16(kf[nk], qa[ks], sc[nk]);
      __builtin_amdgcn_s_setprio(0);
    }

    // ---- per-q max: in-lane over 16 keys, then xor 16/32 across l4 groups
    float m01 = fmaxf(fmaxf(sc[0][0], sc[0][1]), fmaxf(sc[0][2], sc[0][3]));
    float m23 = fmaxf(fmaxf(sc[1][0], sc[1][1]), fmaxf(sc[1][2], sc[1][3]));
    float m45 = fmaxf(fmaxf(sc[2][0], sc[2][1]), fmaxf(sc[2][2], sc[2][3]));
    float m67 = fmaxf(fmaxf(sc[3][0], sc[3][1]), fmaxf(sc[3][2], sc[3][3]));
    float m = fmaxf(fmaxf(m01, m23), fmaxf(m45, m67));
    m = fmaxf(m, __shfl_xor(m, 16));
    m = fmaxf(m, __shfl_xor(m, 32));
    const float smax = m;

    // ---- defer-max rescale (T13)
    if (__any(smax > mrun + THR)) {
      float mn = fmaxf(mrun, smax);
      float alpha = EXP2F(mrun - mn);
      mrun = mn;
#pragma unroll
      for (int r = 0; r < 4; ++r) {
        float ar = __shfl(alpha, l4 * 4 + r);
#pragma unroll
        for (int ni = 0; ni < 4; ++ni) o[ni][r] *= ar;
        o5[r] *= ar;
      }
    }

    // ---- P = exp2(sc - m): lane-local, packed in-register (no LDS, no sums)
    float p[4][4];
#pragma unroll
    for (int nk = 0; nk < 4; ++nk)
#pragma unroll
      for (int r = 0; r < 4; ++r)
        p[nk][r] = EXP2F(sc[nk][r] - mrun);

    // ---- PV: o += P @ vT, self-owned-key order; l accumulated via ones-MFMA.
    // k-map per 32-chunk ks: elem j<4 -> key 32ks+4*l4+j; j>=4 -> 32ks+16+4*l4+(j-4).
    // VT's global key permutation makes the matching V-frag contiguous (b128).
#pragma unroll
    for (int ks = 0; ks < 2; ++ks) {
      union { uint32_t d[4]; s16x8 v; } pa;
      pa.d[0] = cvtpk(p[2 * ks][0], p[2 * ks][1]);
      pa.d[1] = cvtpk(p[2 * ks][2], p[2 * ks][3]);
      pa.d[2] = cvtpk(p[2 * ks + 1][0], p[2 * ks + 1][1]);
      pa.d[3] = cvtpk(p[2 * ks + 1][2], p[2 * ks + 1][3]);
      s16x8 vf[4];
#pragma unroll
      for (int ni = 0; ni < 4; ++ni) {
        const int row = ni * 16 + l15;
        const int scv = (((ks << 2) | l4) ^ (l15 & 7)) << 3;
        vf[ni] = *(const s16x8*)&Vt[cur][row * 64 + scv];
      }
      __builtin_amdgcn_s_setprio(1);
#pragma unroll
      for (int ni = 0; ni < 4; ++ni)
        o[ni] = mfma16(pa.v, vf[ni], o[ni]);
      o5 = mfma16(pa.v, onesf, o5);
      __builtin_amdgcn_s_setprio(0);
    }

    __syncthreads();   // all reads of buf `cur` done; next-tile stage drained
  }

  // ---- epilogue: normalize (denominator already in o-layout) and store
#pragma unroll
  for (int r = 0; r < 4; ++r) {
    float inv = 1.0f / o5[r];
    int row = b * 2048 + q0 + l4 * 4 + r;
#pragma unroll
    for (int ni = 0; ni < 4; ++ni)
      ao[(size_t)row * 1024 + h * 64 + ni * 16 + l15] = f2b(o[ni][r] * inv);
  }
}

// ---------------------------------------------------------------- host
extern "C" void kernel_launch(void* const* d_in, const int* in_sizes, int n_in,
                              void* d_out, int out_size, void* d_ws, size_t ws_size,
                              hipStream_t stream) {
  const float* Q  = (const float*)d_in[0];
  const float* K  = (const float*)d_in[1];
  const float* V  = (const float*)d_in[2];
  const float* Wq = (const float*)d_in[3];
  const float* bq = (const float*)d_in[4];
  const float* Wk = (const float*)d_in[5];
  const float* bk = (const float*)d_in[6];
  const float* Wv = (const float*)d_in[7];
  const float* bv = (const float*)d_in[8];
  const float* Wo = (const float*)d_in[9];
  const float* bo = (const float*)d_in[10];
  float* out = (float*)d_out;

  const size_t NI = (size_t)4096 * 1024;
  const size_t NW = (size_t)1024 * 1024;
  u16* XB  = (u16*)d_ws;          // Qb,Kb,Vb bf16 (3*NI)
  u16* WB  = XB + 3 * NI;         // Wq,Wk,Wv,Wo bf16 (4*NW)
  u16* QKV = WB + 4 * NW;         // q,k [B,H,S,dk] bf16 (slot 2 unused)
  u16* VT  = QKV + 3 * NI;        // vT [B,H,dk,S] bf16 (key-permuted)
  u16* AO  = VT + NI;             // attention output bf16 [B*S][D]

  CvtArgs ca;
  ca.src[0] = Q;  ca.dst[0] = XB;
  ca.src[1] = K;  ca.dst[1] = XB + NI;
  ca.src[2] = V;  ca.dst[2] = XB + 2 * NI;
  ca.src[3] = Wq; ca.dst[3] = WB;
  ca.src[4] = Wk; ca.dst[4] = WB + NW;
  ca.src[5] = Wv; ca.dst[5] = WB + 2 * NW;
  ca.src[6] = Wo; ca.dst[6] = WB + 3 * NW;
  ca.cum[0] = 0;     ca.cum[1] = 4096;  ca.cum[2] = 8192;  ca.cum[3] = 12288;
  ca.cum[4] = 13312; ca.cum[5] = 14336; ca.cum[6] = 15360; ca.cum[7] = 16384;
  cvt_all<<<dim3(16384), 256, 0, stream>>>(ca);

  // q,k,v projections (z = 0,1,2); z==0 pre-scales q; z==2 writes permuted VT
  gemm_bt<0><<<dim3(8, 32, 3), 256, 0, stream>>>(XB, WB, bq, bk, bv, QKV, VT, nullptr);
  // attention
  fattn<<<dim3(16, 32), 512, 0, stream>>>(QKV, QKV + NI, VT, AO);
  // output projection
  gemm_bt<1><<<dim3(8, 32, 1), 256, 0, stream>>>(AO, WB + 3 * NW, bo, nullptr, nullptr,
                                                 nullptr, nullptr, out);
}

// Round 7
// 129.133 us; speedup vs baseline: 1.1649x; 1.1266x over previous
//
#include <hip/hip_runtime.h>
#include <stdint.h>

// MultiHeadAttention fused pipeline for MI355X (gfx950).
// B=2, S=2048, D=1024, H=16, dk=64. fp32 in/out, bf16 MFMA compute.

#define AS1 __attribute__((address_space(1)))
#define AS3 __attribute__((address_space(3)))

typedef unsigned short u16;
typedef short s16x8 __attribute__((ext_vector_type(8)));   // 8 bf16 (4 VGPRs) MFMA frag
typedef float f32x4 __attribute__((ext_vector_type(4)));   // MFMA accumulator
typedef u16   u16x4 __attribute__((ext_vector_type(4)));

#if defined(__has_builtin)
#if __has_builtin(__builtin_amdgcn_exp2f)
#define EXP2F(x) __builtin_amdgcn_exp2f(x)
#else
#define EXP2F(x) exp2f(x)
#endif
#else
#define EXP2F(x) exp2f(x)
#endif

__device__ __forceinline__ u16 f2b(float f) {  // fp32 -> bf16 RNE
  union { float f; uint32_t u; } v;
  v.f = f;
  uint32_t r = (v.u + 0x7fffu + ((v.u >> 16) & 1u)) >> 16;
  return (u16)r;
}

// packed fp32x2 -> bf16x2 (1 VALU op; no builtin on gfx950 -> inline asm, T12)
__device__ __forceinline__ uint32_t cvtpk(float lo, float hi) {
  uint32_t r;
  asm("v_cvt_pk_bf16_f32 %0, %1, %2" : "=v"(r) : "v"(lo), "v"(hi));
  return r;
}

__device__ __forceinline__ f32x4 mfma16(s16x8 a, s16x8 b, f32x4 c) {
  return __builtin_amdgcn_mfma_f32_16x16x32_bf16(a, b, c, 0, 0, 0);
}

__device__ __forceinline__ s16x8 ld_g16(const u16* p) {
  return *reinterpret_cast<const s16x8*>(p);
}

// async global->LDS, 16B per lane. LDS dest must be WAVE-UNIFORM base; HW adds lane*16.
// Global SOURCE is per-lane -> swizzled layouts via pre-swizzled source (m173).
__device__ __forceinline__ void stage16(const u16* g, u16* lds_base) {
  __builtin_amdgcn_global_load_lds((const AS1 unsigned int*)g,
                                   (AS3 unsigned int*)lds_base, 16, 0, 0);
}

// ---------------------------------------------------------------- fused fp32 -> bf16 (all 7 tensors)
struct CvtArgs {
  const float* src[7];
  u16* dst[7];
  int cum[8];   // cumulative block ranges
};

__global__ __launch_bounds__(256) void cvt_all(CvtArgs a) {
  const int bx = blockIdx.x;
  int seg = 0;
#pragma unroll
  for (int i = 1; i < 7; ++i) seg += (bx >= a.cum[i]) ? 1 : 0;
  const int off = (bx - a.cum[seg]) * 256 + threadIdx.x;
  float4 f = reinterpret_cast<const float4*>(a.src[seg])[off];
  union { u16 u[4]; uint64_t q; } o;
  o.u[0] = f2b(f.x); o.u[1] = f2b(f.y); o.u[2] = f2b(f.z); o.u[3] = f2b(f.w);
  reinterpret_cast<uint64_t*>(a.dst[seg])[off] = o.q;
}

// ---------------------------------------------------------------- GEMM  C = A @ W^T + bias
// 128x128 tile, BK=64, double-buffered LDS with XOR-chunk swizzle (T2),
// XCD-aware block swizzle (T1). 4 waves, each 64x64 out.
// MODE 0: z in {0,1,2} selects q,k,v.
//   z==0 -> q [B,H,S,dk] bf16, values pre-scaled by log2(e)/sqrt(dk)
//   z==1 -> k [B,H,S,dk] bf16
//   z==2 -> VT [B,H,dk,S] bf16 with keys PERMUTED: key (32ks+16hi+4g+r) stored at
//           pos (32ks+8g+4hi+r)  -> fattn PV B-frag is one contiguous b128.
// MODE 1: out fp32 [4096][1024] (final projection).
template <int MODE>
__global__ __launch_bounds__(256) void gemm_bt(const u16* __restrict__ Abase,
                                               const u16* __restrict__ Wbase,
                                               const float* __restrict__ bias0,
                                               const float* __restrict__ bias1,
                                               const float* __restrict__ bias2,
                                               u16* __restrict__ outb,
                                               u16* __restrict__ vtout,
                                               float* __restrict__ outf) {
  __shared__ u16 As[2][128 * 64];          // 16KB per buffer, chunk-swizzled
  __shared__ u16 Bs[2][128 * 64];
  const int tid = threadIdx.x;
  const int lane = tid & 63;
  const int w = tid >> 6;
  const int wr = w >> 1, wc = w & 1;       // 2x2 wave grid, each wave 64x64

  // T1: XCD-aware bijective swizzle. nwg = 8*32 = 256 (%8==0). XCD x owns
  // sw in [x*32, x*32+32) -> by in [4x,4x+4), all bx -> 3MB L2 footprint/XCD.
  const int bid = blockIdx.y * 8 + blockIdx.x;
  const int sw = (bid & 7) * 32 + (bid >> 3);
  const int n0 = (sw & 7) * 128;
  const int m0 = (sw >> 3) * 128;
  const int z = (MODE == 0) ? blockIdx.z : 0;
  const float QSC = 0.18033688011112042f;  // log2(e) / sqrt(dk)

  const u16* A = Abase + (size_t)z * (4096u * 1024u);
  const u16* W = Wbase + (size_t)z * (1024u * 1024u);
  const float* bias = (MODE == 0) ? (z == 0 ? bias0 : (z == 1 ? bias1 : bias2)) : bias0;
  u16* ob = (MODE == 0) ? (outb + (size_t)z * (4096u * 1024u)) : nullptr;

  const int l15 = lane & 15, l4 = lane >> 4;

  // staging: wave w stages rows [w*32, w*32+32) of each matrix as 4 calls of
  // 8 rows. Per lane: row = base + lane/8, storage chunk = lane&7,
  // logical col = ((lane&7) ^ (row&7)) * 8 elements.
  const int sr = lane >> 3;                 // 0..7 within 8-row group
  const int sx = lane & 7;                  // storage chunk
  const u16* gA[4];
  const u16* gB[4];
#pragma unroll
  for (int j = 0; j < 4; ++j) {
    const int row = w * 32 + j * 8 + sr;
    const int lc = ((sx ^ (row & 7)) << 3);
    gA[j] = A + (size_t)(m0 + row) * 1024 + lc;
    gB[j] = W + (size_t)(n0 + row) * 1024 + lc;
  }

  f32x4 acc[4][4];
#pragma unroll
  for (int i = 0; i < 4; ++i)
#pragma unroll
    for (int j = 0; j < 4; ++j) acc[i][j] = {0.f, 0.f, 0.f, 0.f};

  // prologue: stage K-tile 0
#pragma unroll
  for (int j = 0; j < 4; ++j) {
    stage16(gA[j], &As[0][(w * 32 + j * 8) * 64]);
    stage16(gB[j], &Bs[0][(w * 32 + j * 8) * 64]);
  }
  __syncthreads();

#pragma unroll 2
  for (int t = 0; t < 16; ++t) {
    const int cur = t & 1;
    if (t + 1 < 16) {                       // issue next tile; hides under MFMA
      const int kt = (t + 1) * 64;
#pragma unroll
      for (int j = 0; j < 4; ++j) {
        stage16(gA[j] + kt, &As[cur ^ 1][(w * 32 + j * 8) * 64]);
        stage16(gB[j] + kt, &Bs[cur ^ 1][(w * 32 + j * 8) * 64]);
      }
    }
#pragma unroll
    for (int ks = 0; ks < 2; ++ks) {
      s16x8 af[4], bf[4];
#pragma unroll
      for (int mi = 0; mi < 4; ++mi) {
        const int row = wr * 64 + mi * 16 + l15;
        const int sc_ = (((ks << 2) | l4) ^ (l15 & 7)) << 3;
        af[mi] = *(const s16x8*)&As[cur][row * 64 + sc_];
      }
#pragma unroll
      for (int ni = 0; ni < 4; ++ni) {
        const int row = wc * 64 + ni * 16 + l15;
        const int sc_ = (((ks << 2) | l4) ^ (l15 & 7)) << 3;
        bf[ni] = *(const s16x8*)&Bs[cur][row * 64 + sc_];
      }
      __builtin_amdgcn_s_setprio(1);
#pragma unroll
      for (int mi = 0; mi < 4; ++mi)
#pragma unroll
        for (int ni = 0; ni < 4; ++ni)
          acc[mi][ni] = mfma16(af[mi], bf[ni], acc[mi][ni]);
      __builtin_amdgcn_s_setprio(0);
    }
    __syncthreads();
  }

#pragma unroll
  for (int ni = 0; ni < 4; ++ni) {
    const int col = n0 + wc * 64 + ni * 16 + l15;
    const float bv = bias[col];
#pragma unroll
    for (int mi = 0; mi < 4; ++mi) {
      const int row0 = m0 + wr * 64 + mi * 16 + l4 * 4;
      if (MODE == 0 && z == 2) {
        // V -> VT [B,H,dk,S], permuted key order (see header comment)
        const int b = row0 >> 11, s0 = row0 & 2047;
        const int pos0 = (s0 & ~31) | ((s0 & 12) << 1) | ((s0 & 16) >> 2);
        const int h = col >> 6, d = col & 63;
        u16x4 pk = {f2b(acc[mi][ni][0] + bv), f2b(acc[mi][ni][1] + bv),
                    f2b(acc[mi][ni][2] + bv), f2b(acc[mi][ni][3] + bv)};
        *(u16x4*)&vtout[((size_t)(b * 16 + h) * 64 + d) * 2048 + pos0] = pk;
      } else {
#pragma unroll
        for (int r = 0; r < 4; ++r) {
          float val = acc[mi][ni][r] + bv;
          const int row = row0 + r;
          if (MODE == 0) {
            if (z == 0) val *= QSC;          // fold softmax scale into q
            const int b = row >> 11, s = row & 2047;
            const int h = col >> 6, d = col & 63;
            ob[((size_t)(b * 16 + h) * 2048 + s) * 64 + d] = f2b(val);
          } else {
            outf[(size_t)row * 1024 + col] = val;
          }
        }
      }
    }
  }
}

// ---------------------------------------------------------------- flash attention
// 8 waves x 16 q-rows = 128 q/block; grid (16,32) = 512 blocks = 2 blocks/CU.
// KVBLK=64, K/V double-buffered LDS (XOR-chunk-swizzled via pre-swizzled source).
// Swapped QK^T (lane l15 owns q-row, scores pre-scaled via q). P in REGISTER
// with self-owned-key order; V pre-permuted in global so the matching B-frag is
// one b128 read. Softmax denominator accumulated by MFMA against ones (same
// layout as o -> no shuffles). Loop unrolled x2 so `cur` is compile-time and
// all LDS addresses hoist.
__global__ __launch_bounds__(512, 4) void fattn(const u16* __restrict__ qp,
                                                const u16* __restrict__ kp,
                                                const u16* __restrict__ vt,
                                                u16* __restrict__ ao) {
  __shared__ u16 Kt[2][4096];               // 64 keys x 64 dk, chunk-swizzled
  __shared__ u16 Vt[2][4096];               // 64 d    x 64 keys (perm), chunk-swizzled

  const int lane = threadIdx.x & 63;
  const int w = threadIdx.x >> 6;           // 0..7
  const int bh = blockIdx.y;
  const int b = bh >> 4, h = bh & 15;
  const int q0 = blockIdx.x * 128 + w * 16;
  const u16* qb = qp + (size_t)bh * (2048 * 64);
  const u16* kb = kp + (size_t)bh * (2048 * 64);
  const u16* vb = vt + (size_t)bh * (64 * 2048);
  const int l15 = lane & 15, l4 = lane >> 4;
  const float THR = 8.0f;                   // defer-max threshold (T13), log2 units

  // staging: wave w stages storage chunks [w*64, w*64+64) of each 8KB tile.
  // chunk s -> row s>>3, storage col s&7, logical col = (s&7) ^ (row&7).
  const int srow = (w << 3) + (lane >> 3);
  const int c0 = (((lane & 7) ^ (srow & 7)) << 3);   // logical col in elements

  // Q fragments (persistent): B-operand, lane l15 = q row, l4*8 = k offset.
  // q values already scaled by log2(e)/sqrt(dk).
  s16x8 qa[2];
#pragma unroll
  for (int ks = 0; ks < 2; ++ks)
    qa[ks] = ld_g16(qb + (size_t)(q0 + l15) * 64 + ks * 32 + l4 * 8);

  s16x8 onesf = {(short)0x3F80, (short)0x3F80, (short)0x3F80, (short)0x3F80,
                 (short)0x3F80, (short)0x3F80, (short)0x3F80, (short)0x3F80};

  f32x4 o[4];                               // O[q=l4*4+r][d=ni*16+l15]
  f32x4 o5 = {0.f, 0.f, 0.f, 0.f};          // softmax denominator (same layout)
  float mrun = -1e30f;                      // per-lane running max for q = l15
#pragma unroll
  for (int ni = 0; ni < 4; ++ni) o[ni] = {0.f, 0.f, 0.f, 0.f};

  // prologue: stage tile 0
  stage16(kb + (size_t)srow * 64 + c0, &Kt[0][w * 512]);
  stage16(vb + (size_t)srow * 2048 + c0, &Vt[0][w * 512]);
  __syncthreads();

#pragma unroll 2
  for (int t = 0; t < 32; ++t) {
    const int cur = t & 1;
    if (t + 1 < 32) {                       // issue next tile early
      const int kk = (t + 1) << 6;
      stage16(kb + (size_t)(kk + srow) * 64 + c0, &Kt[cur ^ 1][w * 512]);
      stage16(vb + (size_t)srow * 2048 + kk + c0, &Vt[cur ^ 1][w * 512]);
    }

    // ---- QK^T (swapped): sc[nk] = D[key][q], key = nk*16+l4*4+r, q = l15
    f32x4 sc[4];
#pragma unroll
    for (int nk = 0; nk < 4; ++nk) sc[nk] = {0.f, 0.f, 0.f, 0.f};
#pragma unroll
    for (int ks = 0; ks < 2; ++ks) {
      s16x8 kf[4];
#pragma unroll
      for (int nk = 0; nk < 4; ++nk) {
        const int row = nk * 16 + l15;
        const int scx = (((ks << 2) | l4) ^ (l15 & 7)) << 3;
        kf[nk] = *(const s16x8*)&Kt[cur][row * 64 + scx];
      }
      __builtin_amdgcn_s_setprio(1);
#pragma unroll
      for (int nk = 0; nk < 4; ++nk)
        sc[nk] = mfma16(kf[nk], qa[ks], sc[nk]);
      __builtin_amdgcn_s_setprio(0);
    }

    // ---- per-q max: in-lane over 16 keys, then xor 16/32 across l4 groups
    float m01 = fmaxf(fmaxf(sc[0][0], sc[0][1]), fmaxf(sc[0][2], sc[0][3]));
    float m23 = fmaxf(fmaxf(sc[1][0], sc[1][1]), fmaxf(sc[1][2], sc[1][3]));
    float m45 = fmaxf(fmaxf(sc[2][0], sc[2][1]), fmaxf(sc[2][2], sc[2][3]));
    float m67 = fmaxf(fmaxf(sc[3][0], sc[3][1]), fmaxf(sc[3][2], sc[3][3]));
    float m = fmaxf(fmaxf(m01, m23), fmaxf(m45, m67));
    m = fmaxf(m, __shfl_xor(m, 16));
    m = fmaxf(m, __shfl_xor(m, 32));
    const float smax = m;

    // ---- defer-max rescale (T13)
    if (__any(smax > mrun + THR)) {
      float mn = fmaxf(mrun, smax);
      float alpha = EXP2F(mrun - mn);
      mrun = mn;
#pragma unroll
      for (int r = 0; r < 4; ++r) {
        float ar = __shfl(alpha, l4 * 4 + r);
#pragma unroll
        for (int ni = 0; ni < 4; ++ni) o[ni][r] *= ar;
        o5[r] *= ar;
      }
    }

    // ---- P = exp2(sc - m): lane-local, packed in-register (no LDS, no sums)
    float p[4][4];
#pragma unroll
    for (int nk = 0; nk < 4; ++nk)
#pragma unroll
      for (int r = 0; r < 4; ++r)
        p[nk][r] = EXP2F(sc[nk][r] - mrun);

    // ---- PV: o += P @ vT, self-owned-key order; l accumulated via ones-MFMA.
    // k-map per 32-chunk ks: elem j<4 -> key 32ks+4*l4+j; j>=4 -> 32ks+16+4*l4+(j-4).
    // VT's global key permutation makes the matching V-frag contiguous (b128).
#pragma unroll
    for (int ks = 0; ks < 2; ++ks) {
      union { uint32_t d[4]; s16x8 v; } pa;
      pa.d[0] = cvtpk(p[2 * ks][0], p[2 * ks][1]);
      pa.d[1] = cvtpk(p[2 * ks][2], p[2 * ks][3]);
      pa.d[2] = cvtpk(p[2 * ks + 1][0], p[2 * ks + 1][1]);
      pa.d[3] = cvtpk(p[2 * ks + 1][2], p[2 * ks + 1][3]);
      s16x8 vf[4];
#pragma unroll
      for (int ni = 0; ni < 4; ++ni) {
        const int row = ni * 16 + l15;
        const int scv = (((ks << 2) | l4) ^ (l15 & 7)) << 3;
        vf[ni] = *(const s16x8*)&Vt[cur][row * 64 + scv];
      }
      __builtin_amdgcn_s_setprio(1);
#pragma unroll
      for (int ni = 0; ni < 4; ++ni)
        o[ni] = mfma16(pa.v, vf[ni], o[ni]);
      o5 = mfma16(pa.v, onesf, o5);
      __builtin_amdgcn_s_setprio(0);
    }

    __syncthreads();   // all reads of buf `cur` done; next-tile stage drained
  }

  // ---- epilogue: normalize (denominator already in o-layout) and store
#pragma unroll
  for (int r = 0; r < 4; ++r) {
    float inv = 1.0f / o5[r];
    int row = b * 2048 + q0 + l4 * 4 + r;
#pragma unroll
    for (int ni = 0; ni < 4; ++ni)
      ao[(size_t)row * 1024 + h * 64 + ni * 16 + l15] = f2b(o[ni][r] * inv);
  }
}

// ---------------------------------------------------------------- host
extern "C" void kernel_launch(void* const* d_in, const int* in_sizes, int n_in,
                              void* d_out, int out_size, void* d_ws, size_t ws_size,
                              hipStream_t stream) {
  const float* Q  = (const float*)d_in[0];
  const float* K  = (const float*)d_in[1];
  const float* V  = (const float*)d_in[2];
  const float* Wq = (const float*)d_in[3];
  const float* bq = (const float*)d_in[4];
  const float* Wk = (const float*)d_in[5];
  const float* bk = (const float*)d_in[6];
  const float* Wv = (const float*)d_in[7];
  const float* bv = (const float*)d_in[8];
  const float* Wo = (const float*)d_in[9];
  const float* bo = (const float*)d_in[10];
  float* out = (float*)d_out;

  const size_t NI = (size_t)4096 * 1024;
  const size_t NW = (size_t)1024 * 1024;
  u16* XB  = (u16*)d_ws;          // Qb,Kb,Vb bf16 (3*NI)
  u16* WB  = XB + 3 * NI;         // Wq,Wk,Wv,Wo bf16 (4*NW)
  u16* QKV = WB + 4 * NW;         // q,k [B,H,S,dk] bf16 (slot 2 unused)
  u16* VT  = QKV + 3 * NI;        // vT [B,H,dk,S] bf16 (key-permuted)
  u16* AO  = VT + NI;             // attention output bf16 [B*S][D]

  CvtArgs ca;
  ca.src[0] = Q;  ca.dst[0] = XB;
  ca.src[1] = K;  ca.dst[1] = XB + NI;
  ca.src[2] = V;  ca.dst[2] = XB + 2 * NI;
  ca.src[3] = Wq; ca.dst[3] = WB;
  ca.src[4] = Wk; ca.dst[4] = WB + NW;
  ca.src[5] = Wv; ca.dst[5] = WB + 2 * NW;
  ca.src[6] = Wo; ca.dst[6] = WB + 3 * NW;
  ca.cum[0] = 0;     ca.cum[1] = 4096;  ca.cum[2] = 8192;  ca.cum[3] = 12288;
  ca.cum[4] = 13312; ca.cum[5] = 14336; ca.cum[6] = 15360; ca.cum[7] = 16384;
  cvt_all<<<dim3(16384), 256, 0, stream>>>(ca);

  // q,k,v projections (z = 0,1,2); z==0 pre-scales q; z==2 writes permuted VT
  gemm_bt<0><<<dim3(8, 32, 3), 256, 0, stream>>>(XB, WB, bq, bk, bv, QKV, VT, nullptr);
  // attention
  fattn<<<dim3(16, 32), 512, 0, stream>>>(QKV, QKV + NI, VT, AO);
  // output projection
  gemm_bt<1><<<dim3(8, 32, 1), 256, 0, stream>>>(AO, WB + 3 * NW, bo, nullptr, nullptr,
                                                 nullptr, nullptr, out);
}

// Round 8
// 127.300 us; speedup vs baseline: 1.1817x; 1.0144x over previous
//
#include <hip/hip_runtime.h>
#include <stdint.h>

// MultiHeadAttention fused pipeline for MI355X (gfx950).
// B=2, S=2048, D=1024, H=16, dk=64. fp32 in/out, bf16 MFMA compute.

#define AS1 __attribute__((address_space(1)))
#define AS3 __attribute__((address_space(3)))

typedef unsigned short u16;
typedef short s16x8 __attribute__((ext_vector_type(8)));   // 8 bf16 (4 VGPRs) MFMA frag
typedef float f32x4 __attribute__((ext_vector_type(4)));   // MFMA accumulator
typedef u16   u16x4 __attribute__((ext_vector_type(4)));

#if defined(__has_builtin)
#if __has_builtin(__builtin_amdgcn_exp2f)
#define EXP2F(x) __builtin_amdgcn_exp2f(x)
#else
#define EXP2F(x) exp2f(x)
#endif
#else
#define EXP2F(x) exp2f(x)
#endif

__device__ __forceinline__ u16 f2b(float f) {  // fp32 -> bf16 RNE
  union { float f; uint32_t u; } v;
  v.f = f;
  uint32_t r = (v.u + 0x7fffu + ((v.u >> 16) & 1u)) >> 16;
  return (u16)r;
}

// packed fp32x2 -> bf16x2 (1 VALU op; no builtin on gfx950 -> inline asm, T12)
__device__ __forceinline__ uint32_t cvtpk(float lo, float hi) {
  uint32_t r;
  asm("v_cvt_pk_bf16_f32 %0, %1, %2" : "=v"(r) : "v"(lo), "v"(hi));
  return r;
}

__device__ __forceinline__ float max3f(float a, float b, float c) {
  float r;
  asm("v_max3_f32 %0, %1, %2, %3" : "=v"(r) : "v"(a), "v"(b), "v"(c));
  return r;
}

__device__ __forceinline__ f32x4 mfma16(s16x8 a, s16x8 b, f32x4 c) {
  return __builtin_amdgcn_mfma_f32_16x16x32_bf16(a, b, c, 0, 0, 0);
}

__device__ __forceinline__ s16x8 ld_g16(const u16* p) {
  return *reinterpret_cast<const s16x8*>(p);
}

// async global->LDS, 16B per lane. LDS dest must be WAVE-UNIFORM base; HW adds lane*16.
// Global SOURCE is per-lane -> swizzled layouts via pre-swizzled source (m173).
__device__ __forceinline__ void stage16(const u16* g, u16* lds_base) {
  __builtin_amdgcn_global_load_lds((const AS1 unsigned int*)g,
                                   (AS3 unsigned int*)lds_base, 16, 0, 0);
}

// ---------------------------------------------------------------- fused fp32 -> bf16 (all 7 tensors)
struct CvtArgs {
  const float* src[7];
  u16* dst[7];
  int cum[8];   // cumulative block ranges
};

__global__ __launch_bounds__(256) void cvt_all(CvtArgs a) {
  const int bx = blockIdx.x;
  int seg = 0;
#pragma unroll
  for (int i = 1; i < 7; ++i) seg += (bx >= a.cum[i]) ? 1 : 0;
  const int off = (bx - a.cum[seg]) * 256 + threadIdx.x;
  float4 f = reinterpret_cast<const float4*>(a.src[seg])[off];
  union { u16 u[4]; uint64_t q; } o;
  o.u[0] = f2b(f.x); o.u[1] = f2b(f.y); o.u[2] = f2b(f.z); o.u[3] = f2b(f.w);
  reinterpret_cast<uint64_t*>(a.dst[seg])[off] = o.q;
}

// ---------------------------------------------------------------- GEMM  C = A @ W^T + bias
// 128x128 tile, BK=64, double-buffered LDS with XOR-chunk swizzle (T2),
// XCD-aware block swizzle (T1). 4 waves, each 64x64 out.
// MODE 0: z in {0,1,2} selects q,k,v.
//   z==0 -> q [B,H,S,dk] bf16, values pre-scaled by log2(e)/sqrt(dk)
//   z==1 -> k [B,H,S,dk] bf16
//   z==2 -> VT [B,H,dk,S] bf16 with keys PERMUTED: key (32ks+16hi+4g+r) stored at
//           pos (32ks+8g+4hi+r)  -> fattn PV B-frag is one contiguous b128.
// MODE 1: out fp32 [4096][1024] (final projection).
template <int MODE>
__global__ __launch_bounds__(256) void gemm_bt(const u16* __restrict__ Abase,
                                               const u16* __restrict__ Wbase,
                                               const float* __restrict__ bias0,
                                               const float* __restrict__ bias1,
                                               const float* __restrict__ bias2,
                                               u16* __restrict__ outb,
                                               u16* __restrict__ vtout,
                                               float* __restrict__ outf) {
  __shared__ u16 As[2][128 * 64];          // 16KB per buffer, chunk-swizzled
  __shared__ u16 Bs[2][128 * 64];
  const int tid = threadIdx.x;
  const int lane = tid & 63;
  const int w = tid >> 6;
  const int wr = w >> 1, wc = w & 1;       // 2x2 wave grid, each wave 64x64

  // T1: XCD-aware bijective swizzle. nwg = 8*32 = 256 (%8==0). XCD x owns
  // sw in [x*32, x*32+32) -> by in [4x,4x+4), all bx -> 3MB L2 footprint/XCD.
  const int bid = blockIdx.y * 8 + blockIdx.x;
  const int sw = (bid & 7) * 32 + (bid >> 3);
  const int n0 = (sw & 7) * 128;
  const int m0 = (sw >> 3) * 128;
  const int z = (MODE == 0) ? blockIdx.z : 0;
  const float QSC = 0.18033688011112042f;  // log2(e) / sqrt(dk)

  const u16* A = Abase + (size_t)z * (4096u * 1024u);
  const u16* W = Wbase + (size_t)z * (1024u * 1024u);
  const float* bias = (MODE == 0) ? (z == 0 ? bias0 : (z == 1 ? bias1 : bias2)) : bias0;
  u16* ob = (MODE == 0) ? (outb + (size_t)z * (4096u * 1024u)) : nullptr;

  const int l15 = lane & 15, l4 = lane >> 4;

  // staging: wave w stages rows [w*32, w*32+32) of each matrix as 4 calls of
  // 8 rows. Per lane: row = base + lane/8, storage chunk = lane&7,
  // logical col = ((lane&7) ^ (row&7)) * 8 elements.
  const int sr = lane >> 3;                 // 0..7 within 8-row group
  const int sx = lane & 7;                  // storage chunk
  const u16* gA[4];
  const u16* gB[4];
#pragma unroll
  for (int j = 0; j < 4; ++j) {
    const int row = w * 32 + j * 8 + sr;
    const int lc = ((sx ^ (row & 7)) << 3);
    gA[j] = A + (size_t)(m0 + row) * 1024 + lc;
    gB[j] = W + (size_t)(n0 + row) * 1024 + lc;
  }

  f32x4 acc[4][4];
#pragma unroll
  for (int i = 0; i < 4; ++i)
#pragma unroll
    for (int j = 0; j < 4; ++j) acc[i][j] = {0.f, 0.f, 0.f, 0.f};

  // prologue: stage K-tile 0
#pragma unroll
  for (int j = 0; j < 4; ++j) {
    stage16(gA[j], &As[0][(w * 32 + j * 8) * 64]);
    stage16(gB[j], &Bs[0][(w * 32 + j * 8) * 64]);
  }
  __syncthreads();

#pragma unroll 2
  for (int t = 0; t < 16; ++t) {
    const int cur = t & 1;
    if (t + 1 < 16) {                       // issue next tile; hides under MFMA
      const int kt = (t + 1) * 64;
#pragma unroll
      for (int j = 0; j < 4; ++j) {
        stage16(gA[j] + kt, &As[cur ^ 1][(w * 32 + j * 8) * 64]);
        stage16(gB[j] + kt, &Bs[cur ^ 1][(w * 32 + j * 8) * 64]);
      }
    }
#pragma unroll
    for (int ks = 0; ks < 2; ++ks) {
      s16x8 af[4], bf[4];
#pragma unroll
      for (int mi = 0; mi < 4; ++mi) {
        const int row = wr * 64 + mi * 16 + l15;
        const int sc_ = (((ks << 2) | l4) ^ (l15 & 7)) << 3;
        af[mi] = *(const s16x8*)&As[cur][row * 64 + sc_];
      }
#pragma unroll
      for (int ni = 0; ni < 4; ++ni) {
        const int row = wc * 64 + ni * 16 + l15;
        const int sc_ = (((ks << 2) | l4) ^ (l15 & 7)) << 3;
        bf[ni] = *(const s16x8*)&Bs[cur][row * 64 + sc_];
      }
      __builtin_amdgcn_s_setprio(1);
#pragma unroll
      for (int mi = 0; mi < 4; ++mi)
#pragma unroll
        for (int ni = 0; ni < 4; ++ni)
          acc[mi][ni] = mfma16(af[mi], bf[ni], acc[mi][ni]);
      __builtin_amdgcn_s_setprio(0);
    }
    __syncthreads();
  }

#pragma unroll
  for (int ni = 0; ni < 4; ++ni) {
    const int col = n0 + wc * 64 + ni * 16 + l15;
    const float bv = bias[col];
#pragma unroll
    for (int mi = 0; mi < 4; ++mi) {
      const int row0 = m0 + wr * 64 + mi * 16 + l4 * 4;
      if (MODE == 0 && z == 2) {
        // V -> VT [B,H,dk,S], permuted key order (see header comment)
        const int b = row0 >> 11, s0 = row0 & 2047;
        const int pos0 = (s0 & ~31) | ((s0 & 12) << 1) | ((s0 & 16) >> 2);
        const int h = col >> 6, d = col & 63;
        u16x4 pk = {f2b(acc[mi][ni][0] + bv), f2b(acc[mi][ni][1] + bv),
                    f2b(acc[mi][ni][2] + bv), f2b(acc[mi][ni][3] + bv)};
        *(u16x4*)&vtout[((size_t)(b * 16 + h) * 64 + d) * 2048 + pos0] = pk;
      } else {
#pragma unroll
        for (int r = 0; r < 4; ++r) {
          float val = acc[mi][ni][r] + bv;
          const int row = row0 + r;
          if (MODE == 0) {
            if (z == 0) val *= QSC;          // fold softmax scale into q
            const int b = row >> 11, s = row & 2047;
            const int h = col >> 6, d = col & 63;
            ob[((size_t)(b * 16 + h) * 2048 + s) * 64 + d] = f2b(val);
          } else {
            outf[(size_t)row * 1024 + col] = val;
          }
        }
      }
    }
  }
}

// ---------------------------------------------------------------- flash attention
// 8 waves x 32 q-rows = 256 q/block; grid (8,32) = 256 blocks = 1 block/CU.
// (R5 showed occupancy>8 waves/CU buys nothing; doubling q/wave halves the
// DS-pipe cost per score -- the most-loaded pipe at R7.)
// KVBLK=64, K/V double-buffered LDS (XOR-chunk-swizzled via pre-swizzled source).
// Swapped QK^T (lane l15 owns q-row, scores pre-scaled via q). P in REGISTER,
// self-owned-key order; V pre-permuted in global so PV B-frag is one b128.
// Running max BAKED INTO the QK^T accumulator (sc init = -mrun) -> common path
// P = exp2(sc) with no subtract. mrun starts at 0 (NOT -1e30: catastrophic
// cancellation); THR=8 net rescales if relative max exceeds it (never for
// N(0,1)-scale scores). Softmax denominator via ones-MFMA (o-layout).
__global__ __launch_bounds__(512, 2) void fattn(const u16* __restrict__ qp,
                                                const u16* __restrict__ kp,
                                                const u16* __restrict__ vt,
                                                u16* __restrict__ ao) {
  __shared__ u16 Kt[2][4096];               // 64 keys x 64 dk, chunk-swizzled
  __shared__ u16 Vt[2][4096];               // 64 d    x 64 keys (perm), chunk-swizzled

  const int lane = threadIdx.x & 63;
  const int w = threadIdx.x >> 6;           // 0..7
  const int bh = blockIdx.y;
  const int b = bh >> 4, h = bh & 15;
  const int q0 = blockIdx.x * 256 + w * 32;
  const u16* qb = qp + (size_t)bh * (2048 * 64);
  const u16* kb = kp + (size_t)bh * (2048 * 64);
  const u16* vb = vt + (size_t)bh * (64 * 2048);
  const int l15 = lane & 15, l4 = lane >> 4;
  const float THR = 8.0f;                   // defer-max threshold (T13), log2 units

  // staging: wave w stages storage chunks [w*64, w*64+64) of each 8KB tile.
  // chunk s -> row s>>3, storage col s&7, logical col = (s&7) ^ (row&7).
  const int srow = (w << 3) + (lane >> 3);
  const int c0 = (((lane & 7) ^ (srow & 7)) << 3);   // logical col in elements

  // Q fragments (persistent): B-operand, lane l15 = q row (+16*mi), l4*8 = k.
  // q values already scaled by log2(e)/sqrt(dk).
  s16x8 qa[2][2];
#pragma unroll
  for (int mi = 0; mi < 2; ++mi)
#pragma unroll
    for (int ks = 0; ks < 2; ++ks)
      qa[mi][ks] = ld_g16(qb + (size_t)(q0 + mi * 16 + l15) * 64 + ks * 32 + l4 * 8);

  s16x8 onesf = {(short)0x3F80, (short)0x3F80, (short)0x3F80, (short)0x3F80,
                 (short)0x3F80, (short)0x3F80, (short)0x3F80, (short)0x3F80};

  f32x4 o[2][4];                            // O[q=16mi+l4*4+r][d=ni*16+l15]
  f32x4 o5[2] = {{0.f, 0.f, 0.f, 0.f}, {0.f, 0.f, 0.f, 0.f}};  // denominators
  float mrun[2] = {0.f, 0.f};               // per-lane running max, q = 16mi+l15
#pragma unroll
  for (int mi = 0; mi < 2; ++mi)
#pragma unroll
    for (int ni = 0; ni < 4; ++ni) o[mi][ni] = {0.f, 0.f, 0.f, 0.f};

  // prologue: stage tile 0
  stage16(kb + (size_t)srow * 64 + c0, &Kt[0][w * 512]);
  stage16(vb + (size_t)srow * 2048 + c0, &Vt[0][w * 512]);
  __syncthreads();

#pragma unroll 2
  for (int t = 0; t < 32; ++t) {
    const int cur = t & 1;
    if (t + 1 < 32) {                       // issue next tile early
      const int kk = (t + 1) << 6;
      stage16(kb + (size_t)(kk + srow) * 64 + c0, &Kt[cur ^ 1][w * 512]);
      stage16(vb + (size_t)srow * 2048 + kk + c0, &Vt[cur ^ 1][w * 512]);
    }

    // ---- QK^T (swapped): sc[mi][nk] = D[key][q] - mrun (baked into C-init)
    f32x4 sc[2][4];
#pragma unroll
    for (int mi = 0; mi < 2; ++mi) {
      const float ini = -mrun[mi];
#pragma unroll
      for (int nk = 0; nk < 4; ++nk) sc[mi][nk] = {ini, ini, ini, ini};
    }
#pragma unroll
    for (int ks = 0; ks < 2; ++ks) {
      s16x8 kf[4];
#pragma unroll
      for (int nk = 0; nk < 4; ++nk) {
        const int row = nk * 16 + l15;
        const int scx = (((ks << 2) | l4) ^ (l15 & 7)) << 3;
        kf[nk] = *(const s16x8*)&Kt[cur][row * 64 + scx];
      }
      __builtin_amdgcn_s_setprio(1);
#pragma unroll
      for (int mi = 0; mi < 2; ++mi)
#pragma unroll
        for (int nk = 0; nk < 4; ++nk)
          sc[mi][nk] = mfma16(kf[nk], qa[mi][ks], sc[mi][nk]);
      __builtin_amdgcn_s_setprio(0);
    }

    // ---- per-q relative max: in-lane 16 via max3, then xor 16/32
    float mrel[2];
#pragma unroll
    for (int mi = 0; mi < 2; ++mi) {
      float a = max3f(sc[mi][0][0], sc[mi][0][1], sc[mi][0][2]);
      float c = max3f(sc[mi][1][0], sc[mi][1][1], sc[mi][1][2]);
      float d = max3f(sc[mi][2][0], sc[mi][2][1], sc[mi][2][2]);
      float e = max3f(sc[mi][3][0], sc[mi][3][1], sc[mi][3][2]);
      float f0 = max3f(sc[mi][0][3], sc[mi][1][3], sc[mi][2][3]);
      float m = max3f(max3f(a, c, d), max3f(e, f0, sc[mi][3][3]), -1e30f);
      m = fmaxf(m, __shfl_xor(m, 16));
      m = fmaxf(m, __shfl_xor(m, 32));
      mrel[mi] = m;
    }

    // ---- defer-max (T13): rare; subtract correction into sc in place
    if (__any((mrel[0] > THR) | (mrel[1] > THR))) {
#pragma unroll
      for (int mi = 0; mi < 2; ++mi) {
        const float d = fmaxf(mrel[mi], 0.f);
        mrun[mi] += d;
        const float alpha = EXP2F(-d);
#pragma unroll
        for (int r = 0; r < 4; ++r) {
          float ar = __shfl(alpha, l4 * 4 + r);
#pragma unroll
          for (int ni = 0; ni < 4; ++ni) o[mi][ni][r] *= ar;
          o5[mi][r] *= ar;
        }
#pragma unroll
        for (int nk = 0; nk < 4; ++nk)
#pragma unroll
          for (int r = 0; r < 4; ++r) sc[mi][nk][r] -= d;
      }
    }

    // ---- P = exp2(sc), pack to bf16 pairs (self-owned-key order), PV MFMA
#pragma unroll
    for (int mi = 0; mi < 2; ++mi) {
      float p[4][4];
#pragma unroll
      for (int nk = 0; nk < 4; ++nk)
#pragma unroll
        for (int r = 0; r < 4; ++r)
          p[nk][r] = EXP2F(sc[mi][nk][r]);
#pragma unroll
      for (int ks = 0; ks < 2; ++ks) {
        union { uint32_t d[4]; s16x8 v; } pa;
        pa.d[0] = cvtpk(p[2 * ks][0], p[2 * ks][1]);
        pa.d[1] = cvtpk(p[2 * ks][2], p[2 * ks][3]);
        pa.d[2] = cvtpk(p[2 * ks + 1][0], p[2 * ks + 1][1]);
        pa.d[3] = cvtpk(p[2 * ks + 1][2], p[2 * ks + 1][3]);
        s16x8 vf[4];
#pragma unroll
        for (int ni = 0; ni < 4; ++ni) {
          const int row = ni * 16 + l15;
          const int scv = (((ks << 2) | l4) ^ (l15 & 7)) << 3;
          vf[ni] = *(const s16x8*)&Vt[cur][row * 64 + scv];
        }
        __builtin_amdgcn_s_setprio(1);
#pragma unroll
        for (int ni = 0; ni < 4; ++ni)
          o[mi][ni] = mfma16(pa.v, vf[ni], o[mi][ni]);
        o5[mi] = mfma16(pa.v, onesf, o5[mi]);
        __builtin_amdgcn_s_setprio(0);
      }
    }

    __syncthreads();   // all reads of buf `cur` done; next-tile stage drained
  }

  // ---- epilogue: normalize (denominator already in o-layout) and store
#pragma unroll
  for (int mi = 0; mi < 2; ++mi)
#pragma unroll
    for (int r = 0; r < 4; ++r) {
      float inv = 1.0f / o5[mi][r];
      int row = b * 2048 + q0 + mi * 16 + l4 * 4 + r;
#pragma unroll
      for (int ni = 0; ni < 4; ++ni)
        ao[(size_t)row * 1024 + h * 64 + ni * 16 + l15] = f2b(o[mi][ni][r] * inv);
    }
}

// ---------------------------------------------------------------- host
extern "C" void kernel_launch(void* const* d_in, const int* in_sizes, int n_in,
                              void* d_out, int out_size, void* d_ws, size_t ws_size,
                              hipStream_t stream) {
  const float* Q  = (const float*)d_in[0];
  const float* K  = (const float*)d_in[1];
  const float* V  = (const float*)d_in[2];
  const float* Wq = (const float*)d_in[3];
  const float* bq = (const float*)d_in[4];
  const float* Wk = (const float*)d_in[5];
  const float* bk = (const float*)d_in[6];
  const float* Wv = (const float*)d_in[7];
  const float* bv = (const float*)d_in[8];
  const float* Wo = (const float*)d_in[9];
  const float* bo = (const float*)d_in[10];
  float* out = (float*)d_out;

  const size_t NI = (size_t)4096 * 1024;
  const size_t NW = (size_t)1024 * 1024;
  u16* XB  = (u16*)d_ws;          // Qb,Kb,Vb bf16 (3*NI)
  u16* WB  = XB + 3 * NI;         // Wq,Wk,Wv,Wo bf16 (4*NW)
  u16* QKV = WB + 4 * NW;         // q,k [B,H,S,dk] bf16 (slot 2 unused)
  u16* VT  = QKV + 3 * NI;        // vT [B,H,dk,S] bf16 (key-permuted)
  u16* AO  = VT + NI;             // attention output bf16 [B*S][D]

  CvtArgs ca;
  ca.src[0] = Q;  ca.dst[0] = XB;
  ca.src[1] = K;  ca.dst[1] = XB + NI;
  ca.src[2] = V;  ca.dst[2] = XB + 2 * NI;
  ca.src[3] = Wq; ca.dst[3] = WB;
  ca.src[4] = Wk; ca.dst[4] = WB + NW;
  ca.src[5] = Wv; ca.dst[5] = WB + 2 * NW;
  ca.src[6] = Wo; ca.dst[6] = WB + 3 * NW;
  ca.cum[0] = 0;     ca.cum[1] = 4096;  ca.cum[2] = 8192;  ca.cum[3] = 12288;
  ca.cum[4] = 13312; ca.cum[5] = 14336; ca.cum[6] = 15360; ca.cum[7] = 16384;
  cvt_all<<<dim3(16384), 256, 0, stream>>>(ca);

  // q,k,v projections (z = 0,1,2); z==0 pre-scales q; z==2 writes permuted VT
  gemm_bt<0><<<dim3(8, 32, 3), 256, 0, stream>>>(XB, WB, bq, bk, bv, QKV, VT, nullptr);
  // attention
  fattn<<<dim3(8, 32), 512, 0, stream>>>(QKV, QKV + NI, VT, AO);
  // output projection
  gemm_bt<1><<<dim3(8, 32, 1), 256, 0, stream>>>(AO, WB + 3 * NW, bo, nullptr, nullptr,
                                                 nullptr, nullptr, out);
}